// Round 1
// baseline (2211.086 us; speedup 1.0000x reference)
//
#include <hip/hip_runtime.h>
#include <math.h>

#define NBQ 256      // question rows
#define NBF 5120     // fact rows
#define MROWS 5376   // NBQ + NBF
#define E_ 128
#define H_ 256
#define G4 1024      // 4*H
#define LQ_ 16       // seq len (q and f identical)
#define GIN_ 808
#define NPAIR_ 400
#define CHUNK_B 64
#define CHUNK_ROWS 25600   // CHUNK_B * 400
#define NCHUNK 4

__device__ __forceinline__ float sigmoidf_(float x) { return 1.0f / (1.0f + expf(-x)); }

// ---------------- fused LSTM-step gates GEMM ----------------
// gates[n, j] = sum_k<128 emb[tok(n,t)][k]*Wih[j][k] + sum_k<256 h[n][k]*Whh[j][k] + bih[j]+bhh[j]
// rows 0..255 = question (q weights), 256..5375 = facts (f weights)
__global__ __launch_bounds__(256) void gates_gemm(
    const int* __restrict__ qidx, const int* __restrict__ fidx,
    const float* __restrict__ emb,
    const float* __restrict__ Wih_q, const float* __restrict__ Whh_q,
    const float* __restrict__ bih_q, const float* __restrict__ bhh_q,
    const float* __restrict__ Wih_f, const float* __restrict__ Whh_f,
    const float* __restrict__ bih_f, const float* __restrict__ bhh_f,
    const float* __restrict__ h, float* __restrict__ gates, int t)
{
    __shared__ float As[16][68];
    __shared__ float Bs[16][68];
    const int tid = threadIdx.x;
    const int tx = tid & 15, ty = tid >> 4;
    const int lrow = tid >> 2;          // 0..63
    const int lk = (tid & 3) << 2;      // 0,4,8,12
    const int br = blockIdx.x, bc = blockIdx.y;
    const bool isq = (br < 4);          // rows 0..255
    const float* __restrict__ Wih = isq ? Wih_q : Wih_f;
    const float* __restrict__ Whh = isq ? Whh_q : Whh_f;

    const int n = br * 64 + lrow;
    const int tok = isq ? qidx[n * LQ_ + t] : fidx[(n - NBQ) * LQ_ + t];
    const float* __restrict__ embrow = emb + (size_t)tok * E_;
    const float* __restrict__ hrow = h + (size_t)n * H_;
    const int jrow = bc * 64 + lrow;
    const float* __restrict__ wihrow = Wih + (size_t)jrow * E_;
    const float* __restrict__ whhrow = Whh + (size_t)jrow * H_;

    float acc[4][4] = {};
    for (int kt = 0; kt < 24; ++kt) {   // K = 128 + 256 = 384
        const int k = kt * 16 + lk;
        float4 a4, b4;
        if (k < E_) {
            a4 = *reinterpret_cast<const float4*>(embrow + k);
            b4 = *reinterpret_cast<const float4*>(wihrow + k);
        } else {
            a4 = *reinterpret_cast<const float4*>(hrow + (k - E_));
            b4 = *reinterpret_cast<const float4*>(whhrow + (k - E_));
        }
        As[lk + 0][lrow] = a4.x; As[lk + 1][lrow] = a4.y; As[lk + 2][lrow] = a4.z; As[lk + 3][lrow] = a4.w;
        Bs[lk + 0][lrow] = b4.x; Bs[lk + 1][lrow] = b4.y; Bs[lk + 2][lrow] = b4.z; Bs[lk + 3][lrow] = b4.w;
        __syncthreads();
        #pragma unroll
        for (int kk = 0; kk < 16; ++kk) {
            float a0 = As[kk][ty * 4 + 0], a1 = As[kk][ty * 4 + 1], a2 = As[kk][ty * 4 + 2], a3 = As[kk][ty * 4 + 3];
            float b0 = Bs[kk][tx * 4 + 0], b1 = Bs[kk][tx * 4 + 1], b2 = Bs[kk][tx * 4 + 2], b3 = Bs[kk][tx * 4 + 3];
            acc[0][0] += a0 * b0; acc[0][1] += a0 * b1; acc[0][2] += a0 * b2; acc[0][3] += a0 * b3;
            acc[1][0] += a1 * b0; acc[1][1] += a1 * b1; acc[1][2] += a1 * b2; acc[1][3] += a1 * b3;
            acc[2][0] += a2 * b0; acc[2][1] += a2 * b1; acc[2][2] += a2 * b2; acc[2][3] += a2 * b3;
            acc[3][0] += a3 * b0; acc[3][1] += a3 * b1; acc[3][2] += a3 * b2; acc[3][3] += a3 * b3;
        }
        __syncthreads();
    }
    const float* __restrict__ bih = isq ? bih_q : bih_f;
    const float* __restrict__ bhh = isq ? bhh_q : bhh_f;
    const int r0 = br * 64 + ty * 4;
    const int c0 = bc * 64 + tx * 4;
    #pragma unroll
    for (int i = 0; i < 4; ++i)
        #pragma unroll
        for (int jj = 0; jj < 4; ++jj) {
            const int cc = c0 + jj;
            gates[(size_t)(r0 + i) * G4 + cc] = acc[i][jj] + bih[cc] + bhh[cc];
        }
}

// ---------------- LSTM elementwise update ----------------
__global__ __launch_bounds__(256) void lstm_update(const float* __restrict__ gates,
                                                   float* __restrict__ h, float* __restrict__ c)
{
    const int n = blockIdx.x;
    const int k = threadIdx.x;
    const float* g = gates + (size_t)n * G4;
    const float i = sigmoidf_(g[k]);
    const float f = sigmoidf_(g[256 + k]);
    const float gg = tanhf(g[512 + k]);
    const float o = sigmoidf_(g[768 + k]);
    const size_t idx = (size_t)n * H_ + k;
    const float cn = f * c[idx] + i * gg;
    c[idx] = cn;
    h[idx] = o * tanhf(cn);
}

// ---------------- generic C[M,N] = act(A[M,K] @ B[N,K]^T + bias) ----------------
template <int RELU>
__global__ __launch_bounds__(256) void gemm_nt(
    const float* __restrict__ A, int lda,
    const float* __restrict__ B, int ldb,
    const float* __restrict__ bias,
    float* __restrict__ C, int ldc,
    int M, int N, int K)
{
    __shared__ float As[16][68];
    __shared__ float Bs[16][68];
    const int tid = threadIdx.x;
    const int tx = tid & 15, ty = tid >> 4;
    const int lrow = tid >> 2;
    const int lk = (tid & 3) << 2;
    const int gr = blockIdx.x * 64, gc = blockIdx.y * 64;
    const int ar = gr + lrow;
    const int brr = gc + lrow;
    const float* __restrict__ arow = A + (size_t)ar * lda;
    const float* __restrict__ brow = B + (size_t)brr * ldb;
    const bool aval = ar < M, bval = brr < N;
    float acc[4][4] = {};
    for (int k0 = 0; k0 < K; k0 += 16) {
        float4 a4 = make_float4(0.f, 0.f, 0.f, 0.f), b4 = make_float4(0.f, 0.f, 0.f, 0.f);
        if (aval) a4 = *reinterpret_cast<const float4*>(arow + k0 + lk);
        if (bval) b4 = *reinterpret_cast<const float4*>(brow + k0 + lk);
        As[lk + 0][lrow] = a4.x; As[lk + 1][lrow] = a4.y; As[lk + 2][lrow] = a4.z; As[lk + 3][lrow] = a4.w;
        Bs[lk + 0][lrow] = b4.x; Bs[lk + 1][lrow] = b4.y; Bs[lk + 2][lrow] = b4.z; Bs[lk + 3][lrow] = b4.w;
        __syncthreads();
        #pragma unroll
        for (int kk = 0; kk < 16; ++kk) {
            float a0 = As[kk][ty * 4 + 0], a1 = As[kk][ty * 4 + 1], a2 = As[kk][ty * 4 + 2], a3 = As[kk][ty * 4 + 3];
            float b0 = Bs[kk][tx * 4 + 0], b1 = Bs[kk][tx * 4 + 1], b2 = Bs[kk][tx * 4 + 2], b3 = Bs[kk][tx * 4 + 3];
            acc[0][0] += a0 * b0; acc[0][1] += a0 * b1; acc[0][2] += a0 * b2; acc[0][3] += a0 * b3;
            acc[1][0] += a1 * b0; acc[1][1] += a1 * b1; acc[1][2] += a1 * b2; acc[1][3] += a1 * b3;
            acc[2][0] += a2 * b0; acc[2][1] += a2 * b1; acc[2][2] += a2 * b2; acc[2][3] += a2 * b3;
            acc[3][0] += a3 * b0; acc[3][1] += a3 * b1; acc[3][2] += a3 * b2; acc[3][3] += a3 * b3;
        }
        __syncthreads();
    }
    #pragma unroll
    for (int i = 0; i < 4; ++i)
        #pragma unroll
        for (int jj = 0; jj < 4; ++jj) {
            const int r = gr + ty * 4 + i, cc = gc + tx * 4 + jj;
            if (r < M && cc < N) {
                float v = acc[i][jj] + (bias ? bias[cc] : 0.f);
                if (RELU) v = fmaxf(v, 0.f);
                C[(size_t)r * ldc + cc] = v;
            }
        }
}

// ---------------- add one-hot separator columns into U, V ----------------
// U[(b,i), j] += gW0[j][256+i];  V[(b,i), j] += gW0[j][532+i]
__global__ __launch_bounds__(256) void uv_onehot(const float* __restrict__ gW0,
                                                 float* __restrict__ U, float* __restrict__ V)
{
    const int row = blockIdx.x;       // 0..5119
    const int j = threadIdx.x;        // 0..255
    const int i = row % 20;
    U[(size_t)row * H_ + j] += gW0[(size_t)j * GIN_ + 256 + i];
    V[(size_t)row * H_ + j] += gW0[(size_t)j * GIN_ + 532 + i];
}

// ---------------- rel0[b,i,j,:] = relu(U[b,i] + V[b,j] + Q0[b] + gb0) ----------------
__global__ __launch_bounds__(256) void rel0_kernel(
    const float* __restrict__ U, const float* __restrict__ V,
    const float* __restrict__ Q0, const float* __restrict__ gb0,
    float* __restrict__ out, int b0)
{
    const int row = blockIdx.x * 4 + (threadIdx.x >> 6);   // 0..CHUNK_ROWS-1
    const int k4 = (threadIdx.x & 63) << 2;
    const int bl = row / NPAIR_;
    const int rem = row - bl * NPAIR_;
    const int oi = rem % 20, oj = rem / 20;
    const int b = b0 + bl;
    const float4 u = *reinterpret_cast<const float4*>(U + (size_t)(b * 20 + oi) * H_ + k4);
    const float4 v = *reinterpret_cast<const float4*>(V + (size_t)(b * 20 + oj) * H_ + k4);
    const float4 q = *reinterpret_cast<const float4*>(Q0 + (size_t)b * H_ + k4);
    const float4 bb = *reinterpret_cast<const float4*>(gb0 + k4);
    float4 o;
    o.x = fmaxf(u.x + v.x + q.x + bb.x, 0.f);
    o.y = fmaxf(u.y + v.y + q.y + bb.y, 0.f);
    o.z = fmaxf(u.z + v.z + q.z + bb.z, 0.f);
    o.w = fmaxf(u.w + v.w + q.w + bb.w, 0.f);
    *reinterpret_cast<float4*>(out + (size_t)row * H_ + k4) = o;
}

// ---------------- rel_sum[b0+bl, k] = sum over 400 pairs ----------------
__global__ __launch_bounds__(256) void sum400(const float* __restrict__ rel,
                                              float* __restrict__ rel_sum, int b0)
{
    const int bl = blockIdx.x;     // 0..63
    const int k = threadIdx.x;
    const float* base = rel + (size_t)bl * NPAIR_ * H_ + k;
    float s = 0.f;
    #pragma unroll 4
    for (int p = 0; p < NPAIR_; ++p) s += base[(size_t)p * H_];
    rel_sum[(size_t)(b0 + bl) * H_ + k] = s;
}

extern "C" void kernel_launch(void* const* d_in, const int* in_sizes, int n_in,
                              void* d_out, int out_size, void* d_ws, size_t ws_size,
                              hipStream_t stream)
{
    const int* qidx = (const int*)d_in[0];
    const int* fidx = (const int*)d_in[1];
    const float* emb = (const float*)d_in[2];
    const float* Wih_q = (const float*)d_in[3];
    const float* Whh_q = (const float*)d_in[4];
    const float* bih_q = (const float*)d_in[5];
    const float* bhh_q = (const float*)d_in[6];
    const float* Wih_f = (const float*)d_in[7];
    const float* Whh_f = (const float*)d_in[8];
    const float* bih_f = (const float*)d_in[9];
    const float* bhh_f = (const float*)d_in[10];
    const float* gW0 = (const float*)d_in[11];
    const float* gb0 = (const float*)d_in[12];
    const float* gW1 = (const float*)d_in[13];
    const float* gb1 = (const float*)d_in[14];
    const float* gW2 = (const float*)d_in[15];
    const float* gb2 = (const float*)d_in[16];
    const float* gW3 = (const float*)d_in[17];
    const float* gb3 = (const float*)d_in[18];
    const float* fW0 = (const float*)d_in[19];
    const float* fb0 = (const float*)d_in[20];
    const float* fW1 = (const float*)d_in[21];
    const float* fb1 = (const float*)d_in[22];
    const float* fW2 = (const float*)d_in[23];
    const float* fb2 = (const float*)d_in[24];
    float* out = (float*)d_out;

    // workspace layout (floats); total ~97.3 MB
    float* ws = (float*)d_ws;
    float* h = ws;                                  // [5376,256]
    float* c = h + (size_t)MROWS * H_;              // [5376,256]
    float* gates = c + (size_t)MROWS * H_;          // [5376,1024]
    float* U = gates + (size_t)MROWS * G4;          // [5120,256]
    float* V = U + (size_t)NBF * H_;                // [5120,256]
    float* Q0 = V + (size_t)NBF * H_;               // [256,256]
    float* rel_a = Q0 + (size_t)NBQ * H_;           // [25600,256]
    float* rel_b = rel_a + (size_t)CHUNK_ROWS * H_; // [25600,256]
    float* rel_sum = rel_b + (size_t)CHUNK_ROWS * H_; // [256,256]
    float* fout1 = rel_sum + (size_t)NBQ * H_;      // [256,256]
    float* fout2 = fout1 + (size_t)NBQ * 256;       // [256,512]

    // zero-init h and c (adjacent)
    hipMemsetAsync(h, 0, (size_t)2 * MROWS * H_ * sizeof(float), stream);

    // 16 LSTM steps (q and f batched in one GEMM, different weights per row-block)
    for (int t = 0; t < 16; ++t) {
        gates_gemm<<<dim3(MROWS / 64, G4 / 64), 256, 0, stream>>>(
            qidx, fidx, emb, Wih_q, Whh_q, bih_q, bhh_q,
            Wih_f, Whh_f, bih_f, bhh_f, h, gates, t);
        lstm_update<<<MROWS, 256, 0, stream>>>(gates, h, c);
    }

    // U = fh @ W0[:,0:256]^T ; V = fh @ W0[:,276:532]^T ; Q0 = qh @ W0[:,552:808]^T
    const float* fh = h + (size_t)NBQ * H_;
    gemm_nt<0><<<dim3(NBF / 64, H_ / 64), 256, 0, stream>>>(fh, H_, gW0, GIN_, nullptr, U, H_, NBF, H_, H_);
    gemm_nt<0><<<dim3(NBF / 64, H_ / 64), 256, 0, stream>>>(fh, H_, gW0 + 276, GIN_, nullptr, V, H_, NBF, H_, H_);
    uv_onehot<<<NBF, 256, 0, stream>>>(gW0, U, V);
    gemm_nt<0><<<dim3(NBQ / 64, H_ / 64), 256, 0, stream>>>(h, H_, gW0 + 552, GIN_, nullptr, Q0, H_, NBQ, H_, H_);

    // g-MLP layers 1..3 + pair sum, chunked over batch
    for (int ch = 0; ch < NCHUNK; ++ch) {
        const int b0 = ch * CHUNK_B;
        rel0_kernel<<<CHUNK_ROWS / 4, 256, 0, stream>>>(U, V, Q0, gb0, rel_a, b0);
        gemm_nt<1><<<dim3(CHUNK_ROWS / 64, H_ / 64), 256, 0, stream>>>(rel_a, H_, gW1, H_, gb1, rel_b, H_, CHUNK_ROWS, H_, H_);
        gemm_nt<1><<<dim3(CHUNK_ROWS / 64, H_ / 64), 256, 0, stream>>>(rel_b, H_, gW2, H_, gb2, rel_a, H_, CHUNK_ROWS, H_, H_);
        gemm_nt<1><<<dim3(CHUNK_ROWS / 64, H_ / 64), 256, 0, stream>>>(rel_a, H_, gW3, H_, gb3, rel_b, H_, CHUNK_ROWS, H_, H_);
        sum400<<<CHUNK_B, 256, 0, stream>>>(rel_b, rel_sum, b0);
    }

    // f-MLP: 256 -> 256 -> 512 -> 32, relu after every layer
    gemm_nt<1><<<dim3(NBQ / 64, 256 / 64), 256, 0, stream>>>(rel_sum, H_, fW0, H_, fb0, fout1, H_, NBQ, 256, H_);
    gemm_nt<1><<<dim3(NBQ / 64, 512 / 64), 256, 0, stream>>>(fout1, 256, fW1, 256, fb1, fout2, 512, NBQ, 512, 256);
    gemm_nt<1><<<dim3(NBQ / 64, 1), 256, 0, stream>>>(fout2, 512, fW2, 512, fb2, out, 32, NBQ, 32, 512);
}

// Round 2
// 700.517 us; speedup vs baseline: 3.1564x; 3.1564x over previous
//
#include <hip/hip_runtime.h>
#include <math.h>

typedef __attribute__((ext_vector_type(8))) short short8;
typedef __attribute__((ext_vector_type(4))) float f32x4;
typedef __attribute__((ext_vector_type(4))) unsigned short u16x4;

#define NBQ 256
#define NBF 5120
#define MROWS 5376
#define E_ 128
#define H_ 256
#define DICTP1 50001
#define GIN_ 808
#define CH_ROWS 51200   // 128 batch elems * 400 pairs
#define CH_B 128
#define NCHUNK 2

__device__ __forceinline__ unsigned short f2bf(float x) {
    unsigned int u = __float_as_uint(x);
    u += 0x7fffu + ((u >> 16) & 1u);
    return (unsigned short)(u >> 16);
}
__device__ __forceinline__ float bf2f(unsigned short b) {
    return __uint_as_float(((unsigned int)b) << 16);
}
__device__ __forceinline__ float sigmoidf_(float x) { return 1.0f / (1.0f + expf(-x)); }

__device__ __forceinline__ void gload16(const void* g, void* l) {
    __builtin_amdgcn_global_load_lds((const __attribute__((address_space(1))) void*)g,
                                     (__attribute__((address_space(3))) void*)l, 16, 0, 0);
}
// LDS tile: [128 rows][64 bf16 cols], row = 128 B. XOR swizzle byte^=(row&7)<<4
// keeps ds_read_b128 column reads conflict-free (G4 / T2 recipe).
__device__ __forceinline__ short8 lds_frag(const unsigned char* base, int row, int ko) {
    const int off = (row << 7) + ((ko << 1) ^ ((row & 7) << 4));
    return *reinterpret_cast<const short8*>(base + off);
}

// ---------------- bf16 MFMA GEMM: C[M,N] = act(A[M,K] @ B[N,K]^T + bias) ----------------
// A,B bf16 (ushort), K%64==0, M%128==0, N%128==0. 4 waves, 128x128 tile, BK=64.
template <int RELU, int OBF>
__global__ __launch_bounds__(256) void mm_bf16(
    const unsigned short* __restrict__ A, int lda,
    const unsigned short* __restrict__ B, int ldb,
    const float* __restrict__ bias,
    float* __restrict__ Cf, unsigned short* __restrict__ Cb, int ldc, int K)
{
    __shared__ __align__(16) unsigned char Ash[16384];
    __shared__ __align__(16) unsigned char Bsh[16384];
    const int tid = threadIdx.x, lane = tid & 63, widx = tid >> 6;
    const int wr = widx >> 1, wc = widx & 1;
    const int gr = blockIdx.x * 128, gc = blockIdx.y * 128;
    const int rsub = lane >> 3, cgrp = lane & 7;
    f32x4 acc[4][4] = {};
    for (int kt = 0; kt < K; kt += 64) {
        #pragma unroll
        for (int j = 0; j < 4; ++j) {
            const int ch = (widx << 2) + j;
            const int r = (ch << 3) + rsub;
            const int ce = (cgrp ^ (r & 7)) << 3;   // pre-swizzled source col
            gload16(A + (size_t)(gr + r) * lda + kt + ce, Ash + (ch << 10));
            gload16(B + (size_t)(gc + r) * ldb + kt + ce, Bsh + (ch << 10));
        }
        __syncthreads();
        #pragma unroll
        for (int kk = 0; kk < 64; kk += 32) {
            const int ko = kk + ((lane >> 4) << 3);
            short8 af[4], bfr[4];
            #pragma unroll
            for (int i = 0; i < 4; ++i) {
                af[i]  = lds_frag(Ash, wr * 64 + i * 16 + (lane & 15), ko);
                bfr[i] = lds_frag(Bsh, wc * 64 + i * 16 + (lane & 15), ko);
            }
            #pragma unroll
            for (int mi = 0; mi < 4; ++mi)
                #pragma unroll
                for (int ni = 0; ni < 4; ++ni)
                    acc[mi][ni] = __builtin_amdgcn_mfma_f32_16x16x32_bf16(af[mi], bfr[ni], acc[mi][ni], 0, 0, 0);
        }
        __syncthreads();
    }
    const int rq = (lane >> 4) << 2, cl = lane & 15;
    #pragma unroll
    for (int ni = 0; ni < 4; ++ni) {
        const int n = gc + wc * 64 + ni * 16 + cl;
        const float bv = bias ? bias[n] : 0.f;
        #pragma unroll
        for (int mi = 0; mi < 4; ++mi) {
            #pragma unroll
            for (int rg = 0; rg < 4; ++rg) {
                const int m = gr + wr * 64 + mi * 16 + rq + rg;
                float v = acc[mi][ni][rg] + bv;
                if (RELU) v = fmaxf(v, 0.f);
                if (OBF) Cb[(size_t)m * ldc + n] = f2bf(v);
                else     Cf[(size_t)m * ldc + n] = v;
            }
        }
    }
}

// ---------------- fused LSTM step: gates GEMM + pointwise update ----------------
// B rows permuted so wave (bc,wc) owns all 4 gates for 16 hidden cols -> epilogue
// applies sigmoid/tanh and writes h (bf16, ping-pong) and c (fp32) directly.
__global__ __launch_bounds__(256) void lstm_step(
    const int* __restrict__ qidx, const int* __restrict__ fidx,
    const unsigned short* __restrict__ embb,
    const unsigned short* __restrict__ Wq, const unsigned short* __restrict__ Wf,
    const float* __restrict__ bsq, const float* __restrict__ bsf,
    const unsigned short* __restrict__ hr, unsigned short* __restrict__ hw,
    float* __restrict__ c, int t)
{
    __shared__ __align__(16) unsigned char Ash[16384];
    __shared__ __align__(16) unsigned char Bsh[16384];
    const int tid = threadIdx.x, lane = tid & 63, widx = tid >> 6;
    const int wr = widx >> 1, wc = widx & 1;
    const int gr = blockIdx.x * 128, bc = blockIdx.y;
    const bool isq = (gr < NBQ);
    const unsigned short* W = isq ? Wq : Wf;
    const float* bs = isq ? bsq : bsf;
    const int rsub = lane >> 3, cgrp = lane & 7;
    f32x4 acc[4][4] = {};
    for (int kt = 0; kt < 384; kt += 64) {
        #pragma unroll
        for (int j = 0; j < 4; ++j) {
            const int ch = (widx << 2) + j;
            const int r = (ch << 3) + rsub;
            const int ce = (cgrp ^ (r & 7)) << 3;
            const int n = gr + r;
            const unsigned short* asrc;
            if (kt < E_) {
                const int tok = isq ? qidx[(n << 4) + t] : fidx[((n - NBQ) << 4) + t];
                asrc = embb + (size_t)tok * E_ + kt + ce;
            } else {
                asrc = hr + (size_t)n * H_ + (kt - E_) + ce;
            }
            gload16(asrc, Ash + (ch << 10));
            // B_lds local row r <- global gate-permuted row
            const int grow = (((r & 63) >> 4) << 8) + (bc << 5) + ((r >> 6) << 4) + (r & 15);
            gload16(W + (size_t)grow * 384 + kt + ce, Bsh + (ch << 10));
        }
        __syncthreads();
        #pragma unroll
        for (int kk = 0; kk < 64; kk += 32) {
            const int ko = kk + ((lane >> 4) << 3);
            short8 af[4], bfr[4];
            #pragma unroll
            for (int i = 0; i < 4; ++i) {
                af[i]  = lds_frag(Ash, wr * 64 + i * 16 + (lane & 15), ko);
                bfr[i] = lds_frag(Bsh, wc * 64 + i * 16 + (lane & 15), ko);
            }
            #pragma unroll
            for (int mi = 0; mi < 4; ++mi)
                #pragma unroll
                for (int ni = 0; ni < 4; ++ni)   // ni == gate index
                    acc[mi][ni] = __builtin_amdgcn_mfma_f32_16x16x32_bf16(af[mi], bfr[ni], acc[mi][ni], 0, 0, 0);
        }
        __syncthreads();
    }
    const int hcol = (bc << 5) + (wc << 4) + (lane & 15);
    float bsv[4];
    #pragma unroll
    for (int g = 0; g < 4; ++g) bsv[g] = bs[(g << 8) + hcol];
    #pragma unroll
    for (int mi = 0; mi < 4; ++mi) {
        #pragma unroll
        for (int rg = 0; rg < 4; ++rg) {
            const int m = gr + wr * 64 + mi * 16 + ((lane >> 4) << 2) + rg;
            const float iv = sigmoidf_(acc[mi][0][rg] + bsv[0]);
            const float fv = sigmoidf_(acc[mi][1][rg] + bsv[1]);
            const float gv = tanhf(acc[mi][2][rg] + bsv[2]);
            const float ov = sigmoidf_(acc[mi][3][rg] + bsv[3]);
            const size_t idx = (size_t)m * H_ + hcol;
            const float cn = fv * c[idx] + iv * gv;
            c[idx] = cn;
            hw[idx] = f2bf(ov * tanhf(cn));
        }
    }
}

// ---------------- packing / conversion kernels ----------------
__global__ void cvt_bf16(const float* __restrict__ s, unsigned short* __restrict__ d, int n) {
    for (int i = blockIdx.x * blockDim.x + threadIdx.x; i < n; i += gridDim.x * blockDim.x)
        d[i] = f2bf(s[i]);
}

__global__ void pack_lstm_w(const float* __restrict__ Wih, const float* __restrict__ Whh,
                            const float* __restrict__ bih, const float* __restrict__ bhh,
                            unsigned short* __restrict__ Wc, float* __restrict__ bsum) {
    const int r = blockIdx.x;       // 0..1023
    const int cx = threadIdx.x;     // 0..383
    const float v = (cx < E_) ? Wih[r * E_ + cx] : Whh[r * H_ + cx - E_];
    Wc[r * 384 + cx] = f2bf(v);
    if (cx == 0) bsum[r] = bih[r] + bhh[r];
}

__global__ __launch_bounds__(256) void pack_w0(const float* __restrict__ gW0, const float* __restrict__ gb0,
                                               unsigned short* __restrict__ W0ab, unsigned short* __restrict__ W0c,
                                               float* __restrict__ sepU, float* __restrict__ sepV) {
    const int idx = blockIdx.x * 256 + threadIdx.x;   // 0..206847
    if (idx < 131072) {                                // W0ab [512][256]
        const int r = idx >> 8, cc = idx & 255;
        const float v = (r < 256) ? gW0[(size_t)r * GIN_ + cc] : gW0[(size_t)(r - 256) * GIN_ + 276 + cc];
        W0ab[idx] = f2bf(v);
    } else if (idx < 196608) {                         // W0c [256][256]
        const int l = idx - 131072;
        const int r = l >> 8, cc = l & 255;
        W0c[l] = f2bf(gW0[(size_t)r * GIN_ + 552 + cc]);
    } else if (idx < 201728) {                         // sepU[i][j] = W0[j][256+i] + gb0[j]
        const int l = idx - 196608;
        const int i = l >> 8, j = l & 255;
        sepU[l] = gW0[(size_t)j * GIN_ + 256 + i] + gb0[j];
    } else {                                           // sepV[i][j] = W0[j][532+i]
        const int l = idx - 201728;
        const int i = l >> 8, j = l & 255;
        sepV[l] = gW0[(size_t)j * GIN_ + 532 + i];
    }
}

// ---------------- rel0: relu(U[b,oi] + V[b,oj] + Q0[b] + sep terms) -> bf16 ----------------
__global__ __launch_bounds__(256) void rel0_kernel(
    const float* __restrict__ UV, const float* __restrict__ Q0,
    const float* __restrict__ sepU, const float* __restrict__ sepV,
    unsigned short* __restrict__ out, int row0)
{
    const int row = blockIdx.x * 4 + (threadIdx.x >> 6);   // chunk-local
    const int k4 = (threadIdx.x & 63) << 2;
    const int grow = row0 + row;
    const int b = grow / 400;
    const int rem = grow - b * 400;
    const int oi = rem % 20, oj = rem / 20;
    const float4 u  = *(const float4*)(UV + (size_t)(b * 20 + oi) * 512 + k4);
    const float4 v  = *(const float4*)(UV + (size_t)(b * 20 + oj) * 512 + 256 + k4);
    const float4 q  = *(const float4*)(Q0 + (size_t)b * H_ + k4);
    const float4 su = *(const float4*)(sepU + oi * H_ + k4);
    const float4 sv = *(const float4*)(sepV + oj * H_ + k4);
    u16x4 o;
    o.x = f2bf(fmaxf(u.x + v.x + q.x + su.x + sv.x, 0.f));
    o.y = f2bf(fmaxf(u.y + v.y + q.y + su.y + sv.y, 0.f));
    o.z = f2bf(fmaxf(u.z + v.z + q.z + su.z + sv.z, 0.f));
    o.w = f2bf(fmaxf(u.w + v.w + q.w + su.w + sv.w, 0.f));
    *(u16x4*)(out + (size_t)row * H_ + k4) = o;
}

__global__ __launch_bounds__(256) void sum400(const unsigned short* __restrict__ rel,
                                              float* __restrict__ rel_sum, int b0)
{
    const int bl = blockIdx.x;
    const int k = threadIdx.x;
    const unsigned short* base = rel + (size_t)bl * 400 * H_ + k;
    float s = 0.f;
    #pragma unroll 4
    for (int p = 0; p < 400; ++p) s += bf2f(base[(size_t)p * H_]);
    rel_sum[(size_t)(b0 + bl) * H_ + k] = s;
}

// ---------------- fp32 GEMM (f-MLP only, small) ----------------
template <int RELU>
__global__ __launch_bounds__(256) void gemm_nt(
    const float* __restrict__ A, int lda,
    const float* __restrict__ B, int ldb,
    const float* __restrict__ bias,
    float* __restrict__ C, int ldc,
    int M, int N, int K)
{
    __shared__ float As[16][68];
    __shared__ float Bs[16][68];
    const int tid = threadIdx.x;
    const int tx = tid & 15, ty = tid >> 4;
    const int lrow = tid >> 2;
    const int lk = (tid & 3) << 2;
    const int gr = blockIdx.x * 64, gc = blockIdx.y * 64;
    const int ar = gr + lrow;
    const int brr = gc + lrow;
    const float* __restrict__ arow = A + (size_t)ar * lda;
    const float* __restrict__ brow = B + (size_t)brr * ldb;
    const bool aval = ar < M, bval = brr < N;
    float acc[4][4] = {};
    for (int k0 = 0; k0 < K; k0 += 16) {
        float4 a4 = make_float4(0.f, 0.f, 0.f, 0.f), b4 = make_float4(0.f, 0.f, 0.f, 0.f);
        if (aval) a4 = *reinterpret_cast<const float4*>(arow + k0 + lk);
        if (bval) b4 = *reinterpret_cast<const float4*>(brow + k0 + lk);
        As[lk + 0][lrow] = a4.x; As[lk + 1][lrow] = a4.y; As[lk + 2][lrow] = a4.z; As[lk + 3][lrow] = a4.w;
        Bs[lk + 0][lrow] = b4.x; Bs[lk + 1][lrow] = b4.y; Bs[lk + 2][lrow] = b4.z; Bs[lk + 3][lrow] = b4.w;
        __syncthreads();
        #pragma unroll
        for (int kk = 0; kk < 16; ++kk) {
            float a0 = As[kk][ty * 4 + 0], a1 = As[kk][ty * 4 + 1], a2 = As[kk][ty * 4 + 2], a3 = As[kk][ty * 4 + 3];
            float b0 = Bs[kk][tx * 4 + 0], b1 = Bs[kk][tx * 4 + 1], b2 = Bs[kk][tx * 4 + 2], b3 = Bs[kk][tx * 4 + 3];
            acc[0][0] += a0 * b0; acc[0][1] += a0 * b1; acc[0][2] += a0 * b2; acc[0][3] += a0 * b3;
            acc[1][0] += a1 * b0; acc[1][1] += a1 * b1; acc[1][2] += a1 * b2; acc[1][3] += a1 * b3;
            acc[2][0] += a2 * b0; acc[2][1] += a2 * b1; acc[2][2] += a2 * b2; acc[2][3] += a2 * b3;
            acc[3][0] += a3 * b0; acc[3][1] += a3 * b1; acc[3][2] += a3 * b2; acc[3][3] += a3 * b3;
        }
        __syncthreads();
    }
    #pragma unroll
    for (int i = 0; i < 4; ++i)
        #pragma unroll
        for (int jj = 0; jj < 4; ++jj) {
            const int r = gr + ty * 4 + i, cc = gc + tx * 4 + jj;
            if (r < M && cc < N) {
                float v = acc[i][jj] + (bias ? bias[cc] : 0.f);
                if (RELU) v = fmaxf(v, 0.f);
                C[(size_t)r * ldc + cc] = v;
            }
        }
}

extern "C" void kernel_launch(void* const* d_in, const int* in_sizes, int n_in,
                              void* d_out, int out_size, void* d_ws, size_t ws_size,
                              hipStream_t stream)
{
    const int* qidx = (const int*)d_in[0];
    const int* fidx = (const int*)d_in[1];
    const float* emb = (const float*)d_in[2];
    const float* Wih_q = (const float*)d_in[3];
    const float* Whh_q = (const float*)d_in[4];
    const float* bih_q = (const float*)d_in[5];
    const float* bhh_q = (const float*)d_in[6];
    const float* Wih_f = (const float*)d_in[7];
    const float* Whh_f = (const float*)d_in[8];
    const float* bih_f = (const float*)d_in[9];
    const float* bhh_f = (const float*)d_in[10];
    const float* gW0 = (const float*)d_in[11];
    const float* gb0 = (const float*)d_in[12];
    const float* gW1 = (const float*)d_in[13];
    const float* gb1 = (const float*)d_in[14];
    const float* gW2 = (const float*)d_in[15];
    const float* gb2 = (const float*)d_in[16];
    const float* gW3 = (const float*)d_in[17];
    const float* gb3 = (const float*)d_in[18];
    const float* fW0 = (const float*)d_in[19];
    const float* fb0 = (const float*)d_in[20];
    const float* fW1 = (const float*)d_in[21];
    const float* fb1 = (const float*)d_in[22];
    const float* fW2 = (const float*)d_in[23];
    const float* fb2 = (const float*)d_in[24];
    float* out = (float*)d_out;

    // ---- workspace layout (bytes), total ~89.4 MB ----
    char* w = (char*)d_ws;
    float* c = (float*)w;                    w += (size_t)MROWS * H_ * 4;      // 5505024
    unsigned short* hb0 = (unsigned short*)w; w += (size_t)MROWS * H_ * 2;     // 2752512
    unsigned short* hb1 = (unsigned short*)w; w += (size_t)MROWS * H_ * 2;
    unsigned short* embb = (unsigned short*)w; w += (size_t)DICTP1 * E_ * 2;   // 12800256
    unsigned short* Wq = (unsigned short*)w;  w += (size_t)1024 * 384 * 2;
    unsigned short* Wf = (unsigned short*)w;  w += (size_t)1024 * 384 * 2;
    float* bsq = (float*)w;                  w += 1024 * 4;
    float* bsf = (float*)w;                  w += 1024 * 4;
    unsigned short* W0ab = (unsigned short*)w; w += (size_t)512 * 256 * 2;
    unsigned short* W0c = (unsigned short*)w;  w += (size_t)256 * 256 * 2;
    unsigned short* gw1b = (unsigned short*)w; w += (size_t)256 * 256 * 2;
    unsigned short* gw2b = (unsigned short*)w; w += (size_t)256 * 256 * 2;
    unsigned short* gw3b = (unsigned short*)w; w += (size_t)256 * 256 * 2;
    float* sepU = (float*)w;                 w += 20 * 256 * 4;
    float* sepV = (float*)w;                 w += 20 * 256 * 4;
    float* UV = (float*)w;                   w += (size_t)NBF * 512 * 4;       // 10485760
    float* Q0 = (float*)w;                   w += (size_t)NBQ * H_ * 4;
    unsigned short* rel_a = (unsigned short*)w; w += (size_t)CH_ROWS * H_ * 2; // 26214400
    unsigned short* rel_b = (unsigned short*)w; w += (size_t)CH_ROWS * H_ * 2;
    float* rel_sum = (float*)w;              w += (size_t)NBQ * H_ * 4;
    float* fout1 = (float*)w;                w += (size_t)NBQ * 256 * 4;
    float* fout2 = (float*)w;                w += (size_t)NBQ * 512 * 4;

    // zero c (fp32) + hb0 (bf16) in one shot (adjacent)
    hipMemsetAsync(c, 0, (size_t)MROWS * H_ * 4 + (size_t)MROWS * H_ * 2, stream);

    // ---- pack/convert (bf16 weights, embedding, sep tables) ----
    cvt_bf16<<<2048, 256, 0, stream>>>(emb, embb, DICTP1 * E_);
    pack_lstm_w<<<1024, 384, 0, stream>>>(Wih_q, Whh_q, bih_q, bhh_q, Wq, bsq);
    pack_lstm_w<<<1024, 384, 0, stream>>>(Wih_f, Whh_f, bih_f, bhh_f, Wf, bsf);
    pack_w0<<<808, 256, 0, stream>>>(gW0, gb0, W0ab, W0c, sepU, sepV);
    cvt_bf16<<<64, 256, 0, stream>>>(gW1, gw1b, 256 * 256);
    cvt_bf16<<<64, 256, 0, stream>>>(gW2, gw2b, 256 * 256);
    cvt_bf16<<<64, 256, 0, stream>>>(gW3, gw3b, 256 * 256);

    // ---- 16 fused LSTM steps (h ping-pong: t even reads hb0, writes hb1) ----
    for (int t = 0; t < 16; ++t) {
        const unsigned short* hr = (t & 1) ? hb1 : hb0;
        unsigned short* hw = (t & 1) ? hb0 : hb1;
        lstm_step<<<dim3(MROWS / 128, 8), 256, 0, stream>>>(
            qidx, fidx, embb, Wq, Wf, bsq, bsf, hr, hw, c, t);
    }
    const unsigned short* hfin = hb0;   // t=15 writes hb0

    // ---- U|V = fh @ W0ab^T  [5120,512] fp32 ; Q0 = qh @ W0c^T [256,256] ----
    const unsigned short* fh = hfin + (size_t)NBQ * H_;
    mm_bf16<0, 0><<<dim3(NBF / 128, 4), 256, 0, stream>>>(fh, H_, W0ab, H_, nullptr, UV, nullptr, 512, H_);
    mm_bf16<0, 0><<<dim3(NBQ / 128, 2), 256, 0, stream>>>(hfin, H_, W0c, H_, nullptr, Q0, nullptr, H_, H_);

    // ---- g-MLP layers (bf16 MFMA) + pair sum, 2 chunks of 128 batch elems ----
    for (int ch = 0; ch < NCHUNK; ++ch) {
        const int row0 = ch * CH_ROWS;
        rel0_kernel<<<CH_ROWS / 4, 256, 0, stream>>>(UV, Q0, sepU, sepV, rel_a, row0);
        mm_bf16<1, 1><<<dim3(CH_ROWS / 128, 2), 256, 0, stream>>>(rel_a, H_, gw1b, H_, gb1, nullptr, rel_b, H_, H_);
        mm_bf16<1, 1><<<dim3(CH_ROWS / 128, 2), 256, 0, stream>>>(rel_b, H_, gw2b, H_, gb2, nullptr, rel_a, H_, H_);
        mm_bf16<1, 1><<<dim3(CH_ROWS / 128, 2), 256, 0, stream>>>(rel_a, H_, gw3b, H_, gb3, nullptr, rel_b, H_, H_);
        sum400<<<CH_B, 256, 0, stream>>>(rel_b, rel_sum, ch * CH_B);
    }

    // ---- f-MLP (fp32, small): 256 -> 256 -> 512 -> 32 ----
    gemm_nt<1><<<dim3(NBQ / 64, 256 / 64), 256, 0, stream>>>(rel_sum, H_, fW0, H_, fb0, fout1, H_, NBQ, 256, H_);
    gemm_nt<1><<<dim3(NBQ / 64, 512 / 64), 256, 0, stream>>>(fout1, 256, fW1, 256, fb1, fout2, 512, NBQ, 512, 256);
    gemm_nt<1><<<dim3(NBQ / 64, 1), 256, 0, stream>>>(fout2, 512, fW2, 512, fb2, out, 32, NBQ, 32, 512);
}

// Round 13
// 635.547 us; speedup vs baseline: 3.4790x; 1.1022x over previous
//
#include <hip/hip_runtime.h>
#include <math.h>

typedef __attribute__((ext_vector_type(8))) short short8;
typedef __attribute__((ext_vector_type(4))) float f32x4;
typedef __attribute__((ext_vector_type(4))) unsigned short u16x4;

#define NBQ 256
#define NBF 5120
#define MROWS 5376
#define E_ 128
#define H_ 256
#define DICTP1 50001
#define GIN_ 808

__device__ __forceinline__ unsigned short f2bf(float x) {
    unsigned int u = __float_as_uint(x);
    u += 0x7fffu + ((u >> 16) & 1u);
    return (unsigned short)(u >> 16);
}
__device__ __forceinline__ float bf2f(unsigned short b) {
    return __uint_as_float(((unsigned int)b) << 16);
}
__device__ __forceinline__ float sigmoidf_(float x) { return 1.0f / (1.0f + expf(-x)); }

__device__ __forceinline__ void gload16(const void* g, void* l) {
    __builtin_amdgcn_global_load_lds((const __attribute__((address_space(1))) void*)g,
                                     (__attribute__((address_space(3))) void*)l, 16, 0, 0);
}
// swizzled LDS fragment reads; row stride 128B / 512B; XOR swizzle byte^=(row&7)<<4
__device__ __forceinline__ short8 frag128(const unsigned char* base, int row, int ko) {
    return *reinterpret_cast<const short8*>(base + (row << 7) + ((ko << 1) ^ ((row & 7) << 4)));
}
__device__ __forceinline__ short8 frag512(const unsigned char* base, int row, int ko) {
    return *reinterpret_cast<const short8*>(base + (row << 9) + ((ko << 1) ^ ((row & 7) << 4)));
}

// ============ fused LSTM step (r2-proven): gates GEMM + pointwise update ============
// B rows gate-permuted so wave (bc,wc) owns all 4 gates for 16 hidden cols.
__global__ __launch_bounds__(256) void lstm_step(
    const int* __restrict__ qidx, const int* __restrict__ fidx,
    const unsigned short* __restrict__ embb,
    const unsigned short* __restrict__ Wq, const unsigned short* __restrict__ Wf,
    const float* __restrict__ bsq, const float* __restrict__ bsf,
    const unsigned short* __restrict__ hr, unsigned short* __restrict__ hw,
    float* __restrict__ c, int t)
{
    __shared__ __align__(16) unsigned char Ash[16384];
    __shared__ __align__(16) unsigned char Bsh[16384];
    const int tid = threadIdx.x, lane = tid & 63, widx = tid >> 6;
    const int wr = widx >> 1, wc = widx & 1;
    const int gr = blockIdx.x * 128, bc = blockIdx.y;
    const bool isq = (gr < NBQ);
    const unsigned short* W = isq ? Wq : Wf;
    const float* bs = isq ? bsq : bsf;
    const int rsub = lane >> 3, cgrp = lane & 7;
    f32x4 acc[4][4] = {};
    for (int kt = 0; kt < 384; kt += 64) {
        #pragma unroll
        for (int j = 0; j < 4; ++j) {
            const int ch = (widx << 2) + j;
            const int r = (ch << 3) + rsub;
            const int ce = (cgrp ^ (r & 7)) << 3;
            const int n = gr + r;
            const unsigned short* asrc;
            if (kt < E_) {
                const int tok = isq ? qidx[(n << 4) + t] : fidx[((n - NBQ) << 4) + t];
                asrc = embb + (size_t)tok * E_ + kt + ce;
            } else {
                asrc = hr + (size_t)n * H_ + (kt - E_) + ce;
            }
            gload16(asrc, Ash + (ch << 10));
            // B_lds local row r <- gate-permuted W row: gate*256 + bc*32 + wc*16 + l15
            const int grow = (((r & 63) >> 4) << 8) + (bc << 5) + ((r >> 6) << 4) + (r & 15);
            gload16(W + (size_t)grow * 384 + kt + ce, Bsh + (ch << 10));
        }
        __syncthreads();
        #pragma unroll
        for (int kk = 0; kk < 64; kk += 32) {
            const int ko = kk + ((lane >> 4) << 3);
            short8 af[4], bfr[4];
            #pragma unroll
            for (int i = 0; i < 4; ++i) {
                af[i]  = frag128(Ash, wr * 64 + i * 16 + (lane & 15), ko);
                bfr[i] = frag128(Bsh, wc * 64 + i * 16 + (lane & 15), ko);
            }
            #pragma unroll
            for (int mi = 0; mi < 4; ++mi)
                #pragma unroll
                for (int ni = 0; ni < 4; ++ni)   // ni == gate index
                    acc[mi][ni] = __builtin_amdgcn_mfma_f32_16x16x32_bf16(af[mi], bfr[ni], acc[mi][ni], 0, 0, 0);
        }
        __syncthreads();
    }
    const int hcol = (bc << 5) + (wc << 4) + (lane & 15);
    float bsv[4];
    #pragma unroll
    for (int g = 0; g < 4; ++g) bsv[g] = bs[(g << 8) + hcol];
    #pragma unroll
    for (int mi = 0; mi < 4; ++mi) {
        #pragma unroll
        for (int rg = 0; rg < 4; ++rg) {
            const int m = gr + wr * 64 + mi * 16 + ((lane >> 4) << 2) + rg;
            const float iv = sigmoidf_(acc[mi][0][rg] + bsv[0]);
            const float fv = sigmoidf_(acc[mi][1][rg] + bsv[1]);
            const float gv = tanhf(acc[mi][2][rg] + bsv[2]);
            const float ov = sigmoidf_(acc[mi][3][rg] + bsv[3]);
            const size_t idx = (size_t)m * H_ + hcol;
            const float cn = fv * c[idx] + iv * gv;
            c[idx] = cn;
            hw[idx] = f2bf(ov * tanhf(cn));
        }
    }
}

// ============ fused g-MLP layers 1-3 + rel0 producer + pair-sum epilogue ============
// 3200 blocks x 32 pair-rows; act ping-pong in LDS; W streamed per 64-k chunk.
__global__ __launch_bounds__(256) void g123sum(
    const float* __restrict__ UV, const float* __restrict__ Q0,
    const float* __restrict__ sepU, const float* __restrict__ sepV,
    const unsigned short* __restrict__ gw1b, const float* __restrict__ gb1,
    const unsigned short* __restrict__ gw2b, const float* __restrict__ gb2,
    const unsigned short* __restrict__ gw3b, const float* __restrict__ gb3,
    float* __restrict__ rel_sum)
{
    __shared__ __align__(16) unsigned char actA[16384];  // [32][256] bf16 swizzled (512B rows)
    __shared__ __align__(16) unsigned char actB[16384];
    __shared__ __align__(16) unsigned char Wsh[32768];   // [256][64] bf16 swizzled
    const int tid = threadIdx.x, lane = tid & 63, widx = tid >> 6;  // 4 waves, each 64 out-cols
    const int grow0 = blockIdx.x << 5;
    {   // rel0 -> actA
        const int r = tid >> 3;
        const int c0 = (tid & 7) << 5;
        const int grow = grow0 + r;
        const int b = grow / 400;
        const int rem = grow - b * 400;
        const int oi = rem % 20, oj = rem / 20;
        const float* up = UV + ((size_t)(b * 20 + oi) << 9);
        const float* vp = UV + ((size_t)(b * 20 + oj) << 9) + 256;
        const float* qp = Q0 + ((size_t)b << 8);
        const float* sup = sepU + (oi << 8);
        const float* svp = sepV + (oj << 8);
        #pragma unroll
        for (int cc = 0; cc < 32; cc += 4) {
            const int c = c0 + cc;
            const float4 u = *(const float4*)(up + c);
            const float4 v = *(const float4*)(vp + c);
            const float4 q = *(const float4*)(qp + c);
            const float4 su = *(const float4*)(sup + c);
            const float4 sv = *(const float4*)(svp + c);
            u16x4 pk;
            pk.x = f2bf(fmaxf(u.x + v.x + q.x + su.x + sv.x, 0.f));
            pk.y = f2bf(fmaxf(u.y + v.y + q.y + su.y + sv.y, 0.f));
            pk.z = f2bf(fmaxf(u.z + v.z + q.z + su.z + sv.z, 0.f));
            pk.w = f2bf(fmaxf(u.w + v.w + q.w + su.w + sv.w, 0.f));
            *(u16x4*)(actA + (r << 9) + (((c << 1) ^ ((r & 7) << 4)))) = pk;
        }
    }
    #pragma unroll 1
    for (int L = 0; L < 3; ++L) {
        const unsigned char* ain = (L & 1) ? actB : actA;      // runtime addrspacecast (OK)
        unsigned char* aout = (L & 1) ? actA : actB;
        const unsigned short* Wp = (L == 0) ? gw1b : (L == 1) ? gw2b : gw3b;
        const float* bl = (L == 0) ? gb1 : (L == 1) ? gb2 : gb3;
        f32x4 acc[2][4] = {};
        for (int kc = 0; kc < 4; ++kc) {
            #pragma unroll
            for (int j = 0; j < 8; ++j) {   // stage W chunk: 32 units, 8 per wave
                const int unit = (widx << 3) + j;
                const int r = (unit << 3) + (lane >> 3);
                const int ce = ((lane & 7) ^ (r & 7)) << 3;
                gload16(Wp + ((size_t)r << 8) + (kc << 6) + ce, Wsh + (unit << 10));
            }
            __syncthreads();
            #pragma unroll
            for (int ks = 0; ks < 2; ++ks) {
                const int kof = (ks << 5) + ((lane >> 4) << 3);
                const int kcol = (kc << 6) + kof;
                short8 af[2], bfr[4];
                af[0] = frag512(ain, (lane & 15), kcol);
                af[1] = frag512(ain, 16 + (lane & 15), kcol);
                #pragma unroll
                for (int ni = 0; ni < 4; ++ni)
                    bfr[ni] = frag128(Wsh, (widx << 6) + (ni << 4) + (lane & 15), kof);
                #pragma unroll
                for (int mi = 0; mi < 2; ++mi)
                    #pragma unroll
                    for (int ni = 0; ni < 4; ++ni)
                        acc[mi][ni] = __builtin_amdgcn_mfma_f32_16x16x32_bf16(af[mi], bfr[ni], acc[mi][ni], 0, 0, 0);
            }
            __syncthreads();
        }
        float bv[4];
        #pragma unroll
        for (int ni = 0; ni < 4; ++ni) bv[ni] = bl[(widx << 6) + (ni << 4) + (lane & 15)];
        if (L < 2) {
            #pragma unroll
            for (int mi = 0; mi < 2; ++mi)
                #pragma unroll
                for (int ni = 0; ni < 4; ++ni)
                    #pragma unroll
                    for (int rg4 = 0; rg4 < 4; ++rg4) {
                        const float v = fmaxf(acc[mi][ni][rg4] + bv[ni], 0.f);
                        const int row = (mi << 4) + ((lane >> 4) << 2) + rg4;
                        const int col = (widx << 6) + (ni << 4) + (lane & 15);
                        *(unsigned short*)(aout + (row << 9) + (((col << 1) ^ ((row & 7) << 4)))) = f2bf(v);
                    }
            // ordering to next layer's reads is provided by its post-stage __syncthreads
        } else {
            const int bstart = grow0 / 400;
            const int rsplit = (bstart + 1) * 400 - grow0;   // rows >= rsplit belong to bstart+1
            const int b1 = (bstart < 255) ? bstart + 1 : 255;
            #pragma unroll
            for (int ni = 0; ni < 4; ++ni) {
                float s0 = 0.f, s1 = 0.f;
                #pragma unroll
                for (int mi = 0; mi < 2; ++mi)
                    #pragma unroll
                    for (int rg4 = 0; rg4 < 4; ++rg4) {
                        const int row = (mi << 4) + ((lane >> 4) << 2) + rg4;
                        const float v = fmaxf(acc[mi][ni][rg4] + bv[ni], 0.f);
                        if (row < rsplit) s0 += v; else s1 += v;
                    }
                s0 += __shfl_xor(s0, 16); s0 += __shfl_xor(s0, 32);
                s1 += __shfl_xor(s1, 16); s1 += __shfl_xor(s1, 32);
                if (lane < 16) {
                    const int col = (widx << 6) + (ni << 4) + lane;
                    atomicAdd(&rel_sum[(bstart << 8) + col], s0);
                    atomicAdd(&rel_sum[(b1 << 8) + col], s1);
                }
            }
        }
    }
}

// ============ bf16 MFMA GEMM (UV / Q0) ============
template <int RELU, int OBF>
__global__ __launch_bounds__(256) void mm_bf16(
    const unsigned short* __restrict__ A, int lda,
    const unsigned short* __restrict__ B, int ldb,
    const float* __restrict__ bias,
    float* __restrict__ Cf, unsigned short* __restrict__ Cb, int ldc, int K)
{
    __shared__ __align__(16) unsigned char Ash[16384];
    __shared__ __align__(16) unsigned char Bsh[16384];
    const int tid = threadIdx.x, lane = tid & 63, widx = tid >> 6;
    const int wr = widx >> 1, wc = widx & 1;
    const int gr = blockIdx.x * 128, gc = blockIdx.y * 128;
    const int rsub = lane >> 3, cgrp = lane & 7;
    f32x4 acc[4][4] = {};
    for (int kt = 0; kt < K; kt += 64) {
        #pragma unroll
        for (int j = 0; j < 4; ++j) {
            const int ch = (widx << 2) + j;
            const int r = (ch << 3) + rsub;
            const int ce = (cgrp ^ (r & 7)) << 3;
            gload16(A + (size_t)(gr + r) * lda + kt + ce, Ash + (ch << 10));
            gload16(B + (size_t)(gc + r) * ldb + kt + ce, Bsh + (ch << 10));
        }
        __syncthreads();
        #pragma unroll
        for (int kk = 0; kk < 64; kk += 32) {
            const int ko = kk + ((lane >> 4) << 3);
            short8 af[4], bfr[4];
            #pragma unroll
            for (int i = 0; i < 4; ++i) {
                af[i]  = frag128(Ash, wr * 64 + i * 16 + (lane & 15), ko);
                bfr[i] = frag128(Bsh, wc * 64 + i * 16 + (lane & 15), ko);
            }
            #pragma unroll
            for (int mi = 0; mi < 4; ++mi)
                #pragma unroll
                for (int ni = 0; ni < 4; ++ni)
                    acc[mi][ni] = __builtin_amdgcn_mfma_f32_16x16x32_bf16(af[mi], bfr[ni], acc[mi][ni], 0, 0, 0);
        }
        __syncthreads();
    }
    const int rq = (lane >> 4) << 2, cl = lane & 15;
    #pragma unroll
    for (int ni = 0; ni < 4; ++ni) {
        const int n = gc + wc * 64 + ni * 16 + cl;
        const float bv = bias ? bias[n] : 0.f;
        #pragma unroll
        for (int mi = 0; mi < 4; ++mi) {
            #pragma unroll
            for (int rg = 0; rg < 4; ++rg) {
                const int m = gr + wr * 64 + mi * 16 + rq + rg;
                float v = acc[mi][ni][rg] + bv;
                if (RELU) v = fmaxf(v, 0.f);
                if (OBF) Cb[(size_t)m * ldc + n] = f2bf(v);
                else     Cf[(size_t)m * ldc + n] = v;
            }
        }
    }
}

// ============ packing / conversion ============
__global__ void cvt_bf16(const float* __restrict__ s, unsigned short* __restrict__ d, int n) {
    for (int i = blockIdx.x * blockDim.x + threadIdx.x; i < n; i += gridDim.x * blockDim.x)
        d[i] = f2bf(s[i]);
}

__global__ void pack_lstm_w(const float* __restrict__ Wih, const float* __restrict__ Whh,
                            const float* __restrict__ bih, const float* __restrict__ bhh,
                            unsigned short* __restrict__ Wc, float* __restrict__ bsum) {
    const int r = blockIdx.x;
    const int cx = threadIdx.x;
    const float v = (cx < E_) ? Wih[r * E_ + cx] : Whh[r * H_ + cx - E_];
    Wc[r * 384 + cx] = f2bf(v);
    if (cx == 0) bsum[r] = bih[r] + bhh[r];
}

__global__ __launch_bounds__(256) void pack_w0(const float* __restrict__ gW0, const float* __restrict__ gb0,
                                               unsigned short* __restrict__ W0ab, unsigned short* __restrict__ W0c,
                                               float* __restrict__ sepU, float* __restrict__ sepV) {
    const int idx = blockIdx.x * 256 + threadIdx.x;
    if (idx < 131072) {
        const int r = idx >> 8, cc = idx & 255;
        const float v = (r < 256) ? gW0[(size_t)r * GIN_ + cc] : gW0[(size_t)(r - 256) * GIN_ + 276 + cc];
        W0ab[idx] = f2bf(v);
    } else if (idx < 196608) {
        const int l = idx - 131072;
        const int r = l >> 8, cc = l & 255;
        W0c[l] = f2bf(gW0[(size_t)r * GIN_ + 552 + cc]);
    } else if (idx < 201728) {
        const int l = idx - 196608;
        const int i = l >> 8, j = l & 255;
        sepU[l] = gW0[(size_t)j * GIN_ + 256 + i] + gb0[j];
    } else {
        const int l = idx - 201728;
        const int i = l >> 8, j = l & 255;
        sepV[l] = gW0[(size_t)j * GIN_ + 532 + i];
    }
}

// ============ fp32 GEMM (f-MLP, small) ============
template <int RELU>
__global__ __launch_bounds__(256) void gemm_nt(
    const float* __restrict__ A, int lda,
    const float* __restrict__ B, int ldb,
    const float* __restrict__ bias,
    float* __restrict__ C, int ldc,
    int M, int N, int K)
{
    __shared__ float As[16][68];
    __shared__ float Bs[16][68];
    const int tid = threadIdx.x;
    const int tx = tid & 15, ty = tid >> 4;
    const int lrow = tid >> 2;
    const int lk = (tid & 3) << 2;
    const int gr = blockIdx.x * 64, gc = blockIdx.y * 64;
    const int ar = gr + lrow;
    const int brr = gc + lrow;
    const float* __restrict__ arow = A + (size_t)ar * lda;
    const float* __restrict__ brow = B + (size_t)brr * ldb;
    const bool aval = ar < M, bval = brr < N;
    float acc[4][4] = {};
    for (int k0 = 0; k0 < K; k0 += 16) {
        float4 a4 = make_float4(0.f, 0.f, 0.f, 0.f), b4 = make_float4(0.f, 0.f, 0.f, 0.f);
        if (aval) a4 = *reinterpret_cast<const float4*>(arow + k0 + lk);
        if (bval) b4 = *reinterpret_cast<const float4*>(brow + k0 + lk);
        As[lk + 0][lrow] = a4.x; As[lk + 1][lrow] = a4.y; As[lk + 2][lrow] = a4.z; As[lk + 3][lrow] = a4.w;
        Bs[lk + 0][lrow] = b4.x; Bs[lk + 1][lrow] = b4.y; Bs[lk + 2][lrow] = b4.z; Bs[lk + 3][lrow] = b4.w;
        __syncthreads();
        #pragma unroll
        for (int kk = 0; kk < 16; ++kk) {
            float a0 = As[kk][ty * 4 + 0], a1 = As[kk][ty * 4 + 1], a2 = As[kk][ty * 4 + 2], a3 = As[kk][ty * 4 + 3];
            float b0 = Bs[kk][tx * 4 + 0], b1 = Bs[kk][tx * 4 + 1], b2 = Bs[kk][tx * 4 + 2], b3 = Bs[kk][tx * 4 + 3];
            acc[0][0] += a0 * b0; acc[0][1] += a0 * b1; acc[0][2] += a0 * b2; acc[0][3] += a0 * b3;
            acc[1][0] += a1 * b0; acc[1][1] += a1 * b1; acc[1][2] += a1 * b2; acc[1][3] += a1 * b3;
            acc[2][0] += a2 * b0; acc[2][1] += a2 * b1; acc[2][2] += a2 * b2; acc[2][3] += a2 * b3;
            acc[3][0] += a3 * b0; acc[3][1] += a3 * b1; acc[3][2] += a3 * b2; acc[3][3] += a3 * b3;
        }
        __syncthreads();
    }
    #pragma unroll
    for (int i = 0; i < 4; ++i)
        #pragma unroll
        for (int jj = 0; jj < 4; ++jj) {
            const int r = gr + ty * 4 + i, cc = gc + tx * 4 + jj;
            if (r < M && cc < N) {
                float v = acc[i][jj] + (bias ? bias[cc] : 0.f);
                if (RELU) v = fmaxf(v, 0.f);
                C[(size_t)r * ldc + cc] = v;
            }
        }
}

extern "C" void kernel_launch(void* const* d_in, const int* in_sizes, int n_in,
                              void* d_out, int out_size, void* d_ws, size_t ws_size,
                              hipStream_t stream)
{
    const int* qidx = (const int*)d_in[0];
    const int* fidx = (const int*)d_in[1];
    const float* emb = (const float*)d_in[2];
    const float* Wih_q = (const float*)d_in[3];
    const float* Whh_q = (const float*)d_in[4];
    const float* bih_q = (const float*)d_in[5];
    const float* bhh_q = (const float*)d_in[6];
    const float* Wih_f = (const float*)d_in[7];
    const float* Whh_f = (const float*)d_in[8];
    const float* bih_f = (const float*)d_in[9];
    const float* bhh_f = (const float*)d_in[10];
    const float* gW0 = (const float*)d_in[11];
    const float* gb0 = (const float*)d_in[12];
    const float* gW1 = (const float*)d_in[13];
    const float* gb1 = (const float*)d_in[14];
    const float* gW2 = (const float*)d_in[15];
    const float* gb2 = (const float*)d_in[16];
    const float* gW3 = (const float*)d_in[17];
    const float* gb3 = (const float*)d_in[18];
    const float* fW0 = (const float*)d_in[19];
    const float* fb0 = (const float*)d_in[20];
    const float* fW1 = (const float*)d_in[21];
    const float* fb1 = (const float*)d_in[22];
    const float* fW2 = (const float*)d_in[23];
    const float* fb2 = (const float*)d_in[24];
    float* out = (float*)d_out;

    // ---- workspace layout (~38 MB) ----
    char* w = (char*)d_ws;
    float* c = (float*)w;                      w += (size_t)MROWS * H_ * 4;   // fp32 cell state
    unsigned short* hb0 = (unsigned short*)w;  w += (size_t)MROWS * H_ * 2;   // adjacent to c for one memset
    unsigned short* hb1 = (unsigned short*)w;  w += (size_t)MROWS * H_ * 2;
    unsigned short* embb = (unsigned short*)w; w += (size_t)DICTP1 * E_ * 2;
    unsigned short* Wq = (unsigned short*)w;   w += (size_t)1024 * 384 * 2;
    unsigned short* Wf = (unsigned short*)w;   w += (size_t)1024 * 384 * 2;
    float* bsq = (float*)w;                    w += 1024 * 4;
    float* bsf = (float*)w;                    w += 1024 * 4;
    unsigned short* W0ab = (unsigned short*)w; w += (size_t)512 * 256 * 2;
    unsigned short* W0c = (unsigned short*)w;  w += (size_t)256 * 256 * 2;
    unsigned short* gw1b = (unsigned short*)w; w += (size_t)256 * 256 * 2;
    unsigned short* gw2b = (unsigned short*)w; w += (size_t)256 * 256 * 2;
    unsigned short* gw3b = (unsigned short*)w; w += (size_t)256 * 256 * 2;
    float* sepU = (float*)w;                   w += 20 * 256 * 4;
    float* sepV = (float*)w;                   w += 20 * 256 * 4;
    float* UV = (float*)w;                     w += (size_t)NBF * 512 * 4;
    float* Q0 = (float*)w;                     w += (size_t)NBQ * H_ * 4;
    float* rel_sum = (float*)w;                w += (size_t)NBQ * H_ * 4;
    float* fout1 = (float*)w;                  w += (size_t)NBQ * 256 * 4;
    float* fout2 = (float*)w;                  w += (size_t)NBQ * 512 * 4;

    // zero c (fp32) + hb0 (bf16) in one shot (adjacent); zero rel_sum accumulator
    (void)hipMemsetAsync(c, 0, (size_t)MROWS * H_ * 4 + (size_t)MROWS * H_ * 2, stream);
    (void)hipMemsetAsync(rel_sum, 0, (size_t)NBQ * H_ * 4, stream);

    // ---- pack/convert ----
    cvt_bf16<<<2048, 256, 0, stream>>>(emb, embb, DICTP1 * E_);
    pack_lstm_w<<<1024, 384, 0, stream>>>(Wih_q, Whh_q, bih_q, bhh_q, Wq, bsq);
    pack_lstm_w<<<1024, 384, 0, stream>>>(Wih_f, Whh_f, bih_f, bhh_f, Wf, bsf);
    pack_w0<<<808, 256, 0, stream>>>(gW0, gb0, W0ab, W0c, sepU, sepV);
    cvt_bf16<<<64, 256, 0, stream>>>(gW1, gw1b, 256 * 256);
    cvt_bf16<<<64, 256, 0, stream>>>(gW2, gw2b, 256 * 256);
    cvt_bf16<<<64, 256, 0, stream>>>(gW3, gw3b, 256 * 256);

    // ---- 16 fused LSTM steps (h ping-pong; final h lands in hb0) ----
    for (int t = 0; t < 16; ++t) {
        const unsigned short* hr = (t & 1) ? hb1 : hb0;
        unsigned short* hw = (t & 1) ? hb0 : hb1;
        lstm_step<<<dim3(MROWS / 128, 8), 256, 0, stream>>>(
            qidx, fidx, embb, Wq, Wf, bsq, bsf, hr, hw, c, t);
    }

    // ---- U|V and Q0 projections ----
    const unsigned short* fh = hb0 + (size_t)NBQ * H_;
    mm_bf16<0, 0><<<dim3(NBF / 128, 4), 256, 0, stream>>>(fh, H_, W0ab, H_, nullptr, UV, nullptr, 512, H_);
    mm_bf16<0, 0><<<dim3(NBQ / 128, 2), 256, 0, stream>>>(hb0, H_, W0c, H_, nullptr, Q0, nullptr, H_, H_);

    // ---- fused rel0 + g1..g3 + pair-sum ----
    g123sum<<<3200, 256, 0, stream>>>(UV, Q0, sepU, sepV, gw1b, gb1, gw2b, gb2, gw3b, gb3, rel_sum);

    // ---- f-MLP: 256 -> 256 -> 512 -> 32 ----
    gemm_nt<1><<<dim3(NBQ / 64, 256 / 64), 256, 0, stream>>>(rel_sum, H_, fW0, H_, fb0, fout1, H_, NBQ, 256, H_);
    gemm_nt<1><<<dim3(NBQ / 64, 512 / 64), 256, 0, stream>>>(fout1, 256, fW1, 256, fb1, fout2, 512, NBQ, 512, 256);
    gemm_nt<1><<<dim3(NBQ / 64, 1), 256, 0, stream>>>(fout2, 512, fW2, 512, fb2, out, 32, NBQ, 32, 512);
}